// Round 1
// baseline (883.749 us; speedup 1.0000x reference)
//
#include <hip/hip_runtime.h>

#define N_NODES 100000
#define N_EDGES 1600000
#define IN_F 128
#define OUT_F 32
#define HEADS 2
#define HO 64  // HEADS*OUT_F

// ---- ordered-int encoding for float atomicMax ----
__device__ __forceinline__ int ordf(float x){ int i=__float_as_int(x); return i>=0 ? i : (i ^ 0x7fffffff); }
__device__ __forceinline__ float unordf(int i){ return __int_as_float(i>=0 ? i : (i ^ 0x7fffffff)); }

__global__ void init_ws_k(float* __restrict__ rst, float* __restrict__ denom, int* __restrict__ m){
  int i = blockIdx.x*blockDim.x + threadIdx.x;
  if (i < N_NODES*HO) rst[i] = 0.f;
  if (i < N_NODES*HEADS){ denom[i] = 0.f; m[i] = (int)0x80000000; }
}

// feat = x @ W  (N x 128 @ 128 x 64), fused el/er per node.
// Grid: ceil(N/64) blocks of 256 threads; each block does 64 nodes in 16 groups of 4.
// Wave w (64 lanes) handles one node; lane = h*32+f is output column.
__global__ void feat_k(const float* __restrict__ x, const float* __restrict__ W,
                       const float* __restrict__ attn_l, const float* __restrict__ attn_r,
                       float* __restrict__ feat, float* __restrict__ el, float* __restrict__ er){
  __shared__ float Ws[IN_F*HO];     // 32 KB
  __shared__ float xs[4][IN_F];     // 2 KB
  int tid = threadIdx.x;
  for (int i = tid; i < IN_F*HO; i += 256) Ws[i] = W[i];
  int w = tid >> 6, lane = tid & 63, h = lane >> 5, f = lane & 31;
  float al = attn_l[lane], ar = attn_r[lane];
  for (int g = 0; g < 16; ++g){
    int node0 = blockIdx.x*64 + g*4;
    __syncthreads();
    for (int i = tid; i < 4*IN_F; i += 256){
      int ln = i >> 7, k = i & 127;
      int n = node0 + ln;
      xs[ln][k] = (n < N_NODES) ? x[(size_t)n*IN_F + k] : 0.f;
    }
    __syncthreads();
    int n = node0 + w;
    if (n < N_NODES){
      float acc = 0.f;
      #pragma unroll
      for (int k = 0; k < IN_F; ++k) acc = fmaf(xs[w][k], Ws[k*HO + lane], acc);
      feat[(size_t)n*HO + lane] = acc;
      float p = acc*al, q = acc*ar;
      #pragma unroll
      for (int off = 16; off; off >>= 1){
        p += __shfl_xor(p, off, 32);
        q += __shfl_xor(q, off, 32);
      }
      if (f == 0){ el[n*HEADS + h] = p; er[n*HEADS + h] = q; }
    }
  }
}

// Fold MLP: wcomb[j] = sum_t W1[j,t]*W2[t];  ccomb = b1.W2 + b2
__global__ void fold_w_k(const float* __restrict__ W1, const float* __restrict__ b1,
                         const float* __restrict__ W2, const float* __restrict__ b2,
                         float* __restrict__ wcomb, float* __restrict__ ccomb){
  int j = threadIdx.x;
  if (j < HO){
    float a = 0.f;
    for (int t = 0; t < OUT_F; ++t) a = fmaf(W1[j*OUT_F + t], W2[t], a);
    wcomb[j] = a;
  }
  if (j == HO){
    float a = 0.f;
    for (int t = 0; t < OUT_F; ++t) a = fmaf(b1[t], W2[t], a);
    *ccomb = a + b2[0];
  }
}

__global__ void edge_max_k(const int* __restrict__ src, const int* __restrict__ dst,
                           const float* __restrict__ el, const float* __restrict__ er,
                           int* __restrict__ m){
  int e = blockIdx.x*blockDim.x + threadIdx.x;
  if (e >= N_EDGES) return;
  int s = src[e], d = dst[e];
  #pragma unroll
  for (int h = 0; h < HEADS; ++h){
    float t = el[s*HEADS + h] + er[d*HEADS + h];
    t = t > 0.f ? t : 0.2f*t;
    atomicMax(&m[d*HEADS + h], ordf(t));
  }
}

__global__ void edge_exp_k(const int* __restrict__ src, const int* __restrict__ dst,
                           const float* __restrict__ el, const float* __restrict__ er,
                           const int* __restrict__ m, float* __restrict__ ex,
                           float* __restrict__ denom){
  int e = blockIdx.x*blockDim.x + threadIdx.x;
  if (e >= N_EDGES) return;
  int s = src[e], d = dst[e];
  #pragma unroll
  for (int h = 0; h < HEADS; ++h){
    float t = el[s*HEADS + h] + er[d*HEADS + h];
    t = t > 0.f ? t : 0.2f*t;
    float mv = unordf(m[d*HEADS + h]);
    float xv = __expf(t - mv);
    ex[(size_t)e*HEADS + h] = xv;
    atomicAdd(&denom[d*HEADS + h], xv);
  }
}

__global__ void recip_k(const float* __restrict__ denom, float* __restrict__ rden){
  int i = blockIdx.x*blockDim.x + threadIdx.x;
  if (i >= N_NODES*HEADS) return;
  float dv = denom[i];
  rden[i] = dv > 0.f ? 1.f/dv : 0.f;
}

// One thread per (edge, col). Wave = one edge: coalesced feat row read,
// coalesced 256B atomicAdd burst into rst[dst].
__global__ void edge_agg_k(const int* __restrict__ src, const int* __restrict__ dst,
                           const float* __restrict__ ex, const float* __restrict__ rden,
                           const float* __restrict__ feat, float* __restrict__ rst){
  int gid = blockIdx.x*blockDim.x + threadIdx.x;
  int e = gid >> 6;
  if (e >= N_EDGES) return;
  int c = gid & 63, h = c >> 5;
  int s = src[e], d = dst[e];
  float alpha = ex[(size_t)e*HEADS + h] * rden[d*HEADS + h];
  atomicAdd(&rst[(size_t)d*HO + c], feat[(size_t)s*HO + c] * alpha);
}

// h = relu(mean over heads of (rst+bias)); s1 = h.wcomb[0:32], s2 = h.wcomb[32:64]
__global__ void node_fold_k(const float* __restrict__ rst, const float* __restrict__ bias,
                            const float* __restrict__ wcomb,
                            float* __restrict__ s1, float* __restrict__ s2){
  int n = blockIdx.x*blockDim.x + threadIdx.x;
  if (n >= N_NODES) return;
  float a1 = 0.f, a2 = 0.f;
  #pragma unroll
  for (int f = 0; f < OUT_F; ++f){
    float hv = 0.5f*((rst[(size_t)n*HO + f] + bias[f]) + (rst[(size_t)n*HO + OUT_F + f] + bias[OUT_F + f]));
    hv = hv > 0.f ? hv : 0.f;
    a1 = fmaf(hv, wcomb[f], a1);
    a2 = fmaf(hv, wcomb[OUT_F + f], a2);
  }
  s1[n] = a1; s2[n] = a2;
}

__global__ void edge_score_k(const int* __restrict__ src, const int* __restrict__ dst,
                             const float* __restrict__ s1, const float* __restrict__ s2,
                             const float* __restrict__ ccomb, float* __restrict__ out){
  int e = blockIdx.x*blockDim.x + threadIdx.x;
  if (e >= N_EDGES) return;
  out[e] = s1[src[e]] + s2[dst[e]] + ccomb[0];
}

extern "C" void kernel_launch(void* const* d_in, const int* in_sizes, int n_in,
                              void* d_out, int out_size, void* d_ws, size_t ws_size,
                              hipStream_t stream){
  const float* x      = (const float*)d_in[0];
  const float* W      = (const float*)d_in[1];
  const float* attn_l = (const float*)d_in[2];
  const float* attn_r = (const float*)d_in[3];
  const float* bias   = (const float*)d_in[4];
  const float* W1     = (const float*)d_in[5];
  const float* b1     = (const float*)d_in[6];
  const float* W2     = (const float*)d_in[7];
  const float* b2     = (const float*)d_in[8];
  const int*   src    = (const int*)d_in[9];
  const int*   dst    = (const int*)d_in[10];
  float* out = (float*)d_out;

  float* ws = (float*)d_ws;
  size_t off = 0;
  float* feat  = ws + off; off += (size_t)N_NODES*HO;
  float* rst   = ws + off; off += (size_t)N_NODES*HO;
  float* ex    = ws + off; off += (size_t)N_EDGES*HEADS;
  float* el    = ws + off; off += (size_t)N_NODES*HEADS;
  float* er    = ws + off; off += (size_t)N_NODES*HEADS;
  int*   m     = (int*)(ws + off); off += (size_t)N_NODES*HEADS;
  float* denom = ws + off; off += (size_t)N_NODES*HEADS;
  float* rden  = ws + off; off += (size_t)N_NODES*HEADS;
  float* s1    = ws + off; off += (size_t)N_NODES;
  float* s2    = ws + off; off += (size_t)N_NODES;
  float* wcomb = ws + off; off += 64;
  float* ccomb = ws + off; off += 1;

  init_ws_k<<<(N_NODES*HO + 255)/256, 256, 0, stream>>>(rst, denom, m);
  feat_k<<<(N_NODES + 63)/64, 256, 0, stream>>>(x, W, attn_l, attn_r, feat, el, er);
  fold_w_k<<<1, 128, 0, stream>>>(W1, b1, W2, b2, wcomb, ccomb);
  edge_max_k<<<(N_EDGES + 255)/256, 256, 0, stream>>>(src, dst, el, er, m);
  edge_exp_k<<<(N_EDGES + 255)/256, 256, 0, stream>>>(src, dst, el, er, m, ex, denom);
  recip_k<<<(N_NODES*HEADS + 255)/256, 256, 0, stream>>>(denom, rden);
  edge_agg_k<<<((size_t)N_EDGES*HO + 255)/256, 256, 0, stream>>>(src, dst, ex, rden, feat, rst);
  node_fold_k<<<(N_NODES + 255)/256, 256, 0, stream>>>(rst, bias, wcomb, s1, s2);
  edge_score_k<<<(N_EDGES + 255)/256, 256, 0, stream>>>(src, dst, s1, s2, ccomb, out);
}

// Round 2
// 570.146 us; speedup vs baseline: 1.5500x; 1.5500x over previous
//
#include <hip/hip_runtime.h>

#define N_NODES 100000
#define N_EDGES 1600000
#define IN_F 128
#define OUT_F 32
#define HEADS 2
#define HO 64  // HEADS*OUT_F

#define SCAN_TILE 2048
#define NB_SCAN ((N_NODES + SCAN_TILE - 1) / SCAN_TILE)  // 49

__global__ void init_ws_k(int* __restrict__ deg, int* __restrict__ cursor){
  int i = blockIdx.x*blockDim.x + threadIdx.x;
  if (i < N_NODES){ deg[i] = 0; cursor[i] = 0; }
}

// feat = x @ W  (N x 128 @ 128 x 64), fused el/er per node.
__global__ void feat_k(const float* __restrict__ x, const float* __restrict__ W,
                       const float* __restrict__ attn_l, const float* __restrict__ attn_r,
                       float* __restrict__ feat, float* __restrict__ el, float* __restrict__ er){
  __shared__ float Ws[IN_F*HO];     // 32 KB
  __shared__ float xs[4][IN_F];     // 2 KB
  int tid = threadIdx.x;
  for (int i = tid; i < IN_F*HO; i += 256) Ws[i] = W[i];
  int w = tid >> 6, lane = tid & 63, h = lane >> 5, f = lane & 31;
  float al = attn_l[lane], ar = attn_r[lane];
  for (int g = 0; g < 16; ++g){
    int node0 = blockIdx.x*64 + g*4;
    __syncthreads();
    for (int i = tid; i < 4*IN_F; i += 256){
      int ln = i >> 7, k = i & 127;
      int n = node0 + ln;
      xs[ln][k] = (n < N_NODES) ? x[(size_t)n*IN_F + k] : 0.f;
    }
    __syncthreads();
    int n = node0 + w;
    if (n < N_NODES){
      float acc = 0.f;
      #pragma unroll
      for (int k = 0; k < IN_F; ++k) acc = fmaf(xs[w][k], Ws[k*HO + lane], acc);
      feat[(size_t)n*HO + lane] = acc;
      float p = acc*al, q = acc*ar;
      #pragma unroll
      for (int off = 16; off; off >>= 1){
        p += __shfl_xor(p, off, 32);
        q += __shfl_xor(q, off, 32);
      }
      if (f == 0){ el[n*HEADS + h] = p; er[n*HEADS + h] = q; }
    }
  }
}

// Fold MLP: wcomb[j] = sum_t W1[j,t]*W2[t];  ccomb = b1.W2 + b2
__global__ void fold_w_k(const float* __restrict__ W1, const float* __restrict__ b1,
                         const float* __restrict__ W2, const float* __restrict__ b2,
                         float* __restrict__ wcomb, float* __restrict__ ccomb){
  int j = threadIdx.x;
  if (j < HO){
    float a = 0.f;
    for (int t = 0; t < OUT_F; ++t) a = fmaf(W1[j*OUT_F + t], W2[t], a);
    wcomb[j] = a;
  }
  if (j == HO){
    float a = 0.f;
    for (int t = 0; t < OUT_F; ++t) a = fmaf(b1[t], W2[t], a);
    *ccomb = a + b2[0];
  }
}

__global__ void hist_k(const int* __restrict__ dst, int* __restrict__ deg){
  int e = blockIdx.x*blockDim.x + threadIdx.x;
  if (e < N_EDGES) atomicAdd(&deg[dst[e]], 1);
}

// exclusive scan, 3 kernels
__global__ void scan1_k(const int* __restrict__ deg, int* __restrict__ exsc, int* __restrict__ tsum){
  __shared__ int sh[256];
  int b = blockIdx.x, t = threadIdx.x;
  int base = b*SCAN_TILE + t*8;
  int v[8]; int local = 0;
  #pragma unroll
  for (int i = 0; i < 8; ++i){
    int idx = base + i;
    v[i] = (idx < N_NODES) ? deg[idx] : 0;
    local += v[i];
  }
  sh[t] = local; __syncthreads();
  for (int off = 1; off < 256; off <<= 1){
    int xv = (t >= off) ? sh[t-off] : 0;
    __syncthreads();
    sh[t] += xv;
    __syncthreads();
  }
  int run = sh[t] - local;   // exclusive thread prefix within tile
  if (t == 255) tsum[b] = sh[255];
  #pragma unroll
  for (int i = 0; i < 8; ++i){
    int idx = base + i;
    if (idx < N_NODES) exsc[idx] = run;
    run += v[i];
  }
}

__global__ void scan2_k(const int* __restrict__ tsum, int* __restrict__ toff){
  __shared__ int sh[64];
  int t = threadIdx.x;
  int v = (t < NB_SCAN) ? tsum[t] : 0;
  sh[t] = v; __syncthreads();
  for (int off = 1; off < 64; off <<= 1){
    int xv = (t >= off) ? sh[t-off] : 0;
    __syncthreads();
    sh[t] += xv;
    __syncthreads();
  }
  if (t < NB_SCAN) toff[t] = sh[t] - v;
}

__global__ void scan3_k(const int* __restrict__ exsc, const int* __restrict__ toff,
                        int* __restrict__ rowptr){
  int b = blockIdx.x, t = threadIdx.x;
  int base = b*SCAN_TILE + t*8;
  int add = toff[b];
  #pragma unroll
  for (int i = 0; i < 8; ++i){
    int idx = base + i;
    if (idx < N_NODES) rowptr[idx] = exsc[idx] + add;
  }
  if (b == 0 && t == 0) rowptr[N_NODES] = N_EDGES;
}

// scatter edges into CSR-by-dst; precompute leaky logits t per head
__global__ void scatter_k(const int* __restrict__ src, const int* __restrict__ dst,
                          const float* __restrict__ el, const float* __restrict__ er,
                          const int* __restrict__ rowptr, int* __restrict__ cursor,
                          int* __restrict__ srcs, float2* __restrict__ tvals){
  int e = blockIdx.x*blockDim.x + threadIdx.x;
  if (e >= N_EDGES) return;
  int s = src[e], d = dst[e];
  int pos = atomicAdd(&cursor[d], 1);
  int idx = rowptr[d] + pos;
  srcs[idx] = s;
  float t0 = el[s*HEADS + 0] + er[d*HEADS + 0];
  float t1 = el[s*HEADS + 1] + er[d*HEADS + 1];
  t0 = t0 > 0.f ? t0 : 0.2f*t0;
  t1 = t1 > 0.f ? t1 : 0.2f*t1;
  tvals[idx] = make_float2(t0, t1);
}

// One wave per dst node: softmax over incoming edges + weighted feat aggregation
// + fused bias/mean/relu/MLP-fold epilogue. No atomics, rst never materialized.
__global__ void node_agg_k(const int* __restrict__ rowptr, const int* __restrict__ srcs,
                           const float2* __restrict__ tvals, const float* __restrict__ feat,
                           const float* __restrict__ bias, const float* __restrict__ wcomb,
                           float* __restrict__ s1, float* __restrict__ s2){
  int wid = (blockIdx.x*blockDim.x + threadIdx.x) >> 6;
  if (wid >= N_NODES) return;
  int lane = threadIdx.x & 63;
  int b = rowptr[wid], e1 = rowptr[wid+1];

  // pass 1: per-head max
  float m0 = -3.402823e38f, m1 = -3.402823e38f;
  for (int j = b + lane; j < e1; j += 64){
    float2 tv = tvals[j];
    m0 = fmaxf(m0, tv.x); m1 = fmaxf(m1, tv.y);
  }
  #pragma unroll
  for (int off = 32; off; off >>= 1){
    m0 = fmaxf(m0, __shfl_xor(m0, off));
    m1 = fmaxf(m1, __shfl_xor(m1, off));
  }
  // pass 2: per-head sum of exp
  float sum0 = 0.f, sum1 = 0.f;
  for (int j = b + lane; j < e1; j += 64){
    float2 tv = tvals[j];
    sum0 += __expf(tv.x - m0); sum1 += __expf(tv.y - m1);
  }
  #pragma unroll
  for (int off = 32; off; off >>= 1){
    sum0 += __shfl_xor(sum0, off);
    sum1 += __shfl_xor(sum1, off);
  }
  float r0 = sum0 > 0.f ? 1.f/sum0 : 0.f;
  float r1 = sum1 > 0.f ? 1.f/sum1 : 0.f;

  // pass 3: aggregate alpha * feat[src]
  int h = lane >> 5;
  float mh = h ? m1 : m0, rh = h ? r1 : r0;
  float acc = 0.f;
  for (int j = b; j < e1; ++j){
    float2 tv = tvals[j];          // broadcast
    float th = h ? tv.y : tv.x;
    float alpha = __expf(th - mh) * rh;
    int s = srcs[j];               // broadcast
    acc = fmaf(alpha, feat[(size_t)s*HO + lane], acc);
  }

  // epilogue: +bias, mean over heads, relu, dot with folded MLP weights
  float accN = acc + bias[lane];
  float other = __shfl_xor(accN, 32);          // pair lane f with lane f+32
  float hv = 0.5f*(accN + other);
  hv = fmaxf(hv, 0.f);                          // lanes 32-63 mirror lanes 0-31
  int f = lane & 31;
  float p = hv * wcomb[f];
  float q = hv * wcomb[32 + f];
  #pragma unroll
  for (int off = 16; off; off >>= 1){           // reduce within each 32-half
    p += __shfl_xor(p, off);
    q += __shfl_xor(q, off);
  }
  if (lane == 0){ s1[wid] = p; s2[wid] = q; }
}

__global__ void edge_score_k(const int* __restrict__ src, const int* __restrict__ dst,
                             const float* __restrict__ s1, const float* __restrict__ s2,
                             const float* __restrict__ ccomb, float* __restrict__ out){
  int e = blockIdx.x*blockDim.x + threadIdx.x;
  if (e >= N_EDGES) return;
  out[e] = s1[src[e]] + s2[dst[e]] + ccomb[0];
}

extern "C" void kernel_launch(void* const* d_in, const int* in_sizes, int n_in,
                              void* d_out, int out_size, void* d_ws, size_t ws_size,
                              hipStream_t stream){
  const float* x      = (const float*)d_in[0];
  const float* W      = (const float*)d_in[1];
  const float* attn_l = (const float*)d_in[2];
  const float* attn_r = (const float*)d_in[3];
  const float* bias   = (const float*)d_in[4];
  const float* W1     = (const float*)d_in[5];
  const float* b1     = (const float*)d_in[6];
  const float* W2     = (const float*)d_in[7];
  const float* b2     = (const float*)d_in[8];
  const int*   src    = (const int*)d_in[9];
  const int*   dst    = (const int*)d_in[10];
  float* out = (float*)d_out;

  float* ws = (float*)d_ws;
  size_t off = 0;
  float*  feat   = ws + off; off += (size_t)N_NODES*HO;        // 6.4M
  float2* tvals  = (float2*)(ws + off); off += (size_t)N_EDGES*2;  // 3.2M floats, 8B-aligned
  float*  el     = ws + off; off += (size_t)N_NODES*HEADS;
  float*  er     = ws + off; off += (size_t)N_NODES*HEADS;
  float*  s1     = ws + off; off += N_NODES;
  float*  s2     = ws + off; off += N_NODES;
  float*  wcomb  = ws + off; off += 64;
  float*  ccomb  = ws + off; off += 64;  // padded
  int*    deg    = (int*)(ws + off); off += N_NODES;
  int*    cursor = (int*)(ws + off); off += N_NODES;
  int*    exsc   = (int*)(ws + off); off += N_NODES;
  int*    rowptr = (int*)(ws + off); off += N_NODES + 1;
  int*    tsum   = (int*)(ws + off); off += NB_SCAN;
  int*    toff   = (int*)(ws + off); off += NB_SCAN + 2;
  int*    srcs   = (int*)(ws + off); off += N_EDGES;

  init_ws_k<<<(N_NODES + 255)/256, 256, 0, stream>>>(deg, cursor);
  feat_k<<<(N_NODES + 63)/64, 256, 0, stream>>>(x, W, attn_l, attn_r, feat, el, er);
  fold_w_k<<<1, 128, 0, stream>>>(W1, b1, W2, b2, wcomb, ccomb);
  hist_k<<<(N_EDGES + 255)/256, 256, 0, stream>>>(dst, deg);
  scan1_k<<<NB_SCAN, 256, 0, stream>>>(deg, exsc, tsum);
  scan2_k<<<1, 64, 0, stream>>>(tsum, toff);
  scan3_k<<<NB_SCAN, 256, 0, stream>>>(exsc, toff, rowptr);
  scatter_k<<<(N_EDGES + 255)/256, 256, 0, stream>>>(src, dst, el, er, rowptr, cursor, srcs, tvals);
  node_agg_k<<<(N_NODES*64 + 255)/256, 256, 0, stream>>>(rowptr, srcs, tvals, feat, bias, wcomb, s1, s2);
  edge_score_k<<<(N_EDGES + 255)/256, 256, 0, stream>>>(src, dst, s1, s2, ccomb, out);
}